// Round 13
// baseline (121.436 us; speedup 1.0000x reference)
//
#include <hip/hip_runtime.h>
#include <stdint.h>

// Segmented top-4 over CSR (N=500K segments, E=32M edges).
// d_out = f32: [N*4 topk_vals][N*4 topk_idx-as-float], 16 MB.
// Pads MUST be bf16-finite (checker compares in bf16; -inf pad => nan).
//
// v8 = v6 scan/merge + WINDOWED degree binning: one LDS counting-sort block
// per 1024-segment window orders segments by k = ceil(deg/32). Waves then
// get 8 equal-k segments (max-of-groups loop waste ~2.6x -> ~1.1x) while a
// segment moves <= 1024 slots, keeping each wave's edge streams inside a
// ~256 KB window (L2-resident) — fixing R12's locality loss. ONE extra
// dispatch (no zero/prefix/global-atomic kernels). ws: [nseg i32 perm].

#define WIN 1024

template <int CTRL>
__device__ __forceinline__ float dppf(float x) {
  int r = __builtin_amdgcn_update_dpp(__float_as_int(x), __float_as_int(x),
                                      CTRL, 0xF, 0xF, false);
  return __int_as_float(r);
}
template <int CTRL>
__device__ __forceinline__ int dppi(int x) {
  return __builtin_amdgcn_update_dpp(x, x, CTRL, 0xF, 0xF, false);
}

// 8-lane reductions: quad_perm xor1 (0xB1), xor2 (0x4E), row_half_mirror
// (0x141) — all stay inside the 8-lane group.
__device__ __forceinline__ float grpmax8(float x) {
  x = fmaxf(x, dppf<0xB1>(x));
  x = fmaxf(x, dppf<0x4E>(x));
  x = fmaxf(x, dppf<0x141>(x));
  return x;
}
__device__ __forceinline__ int grpmin8(int x) {
  x = min(x, dppi<0xB1>(x));
  x = min(x, dppi<0x4E>(x));
  x = min(x, dppi<0x141>(x));
  return x;
}

// ---- windowed counting sort: one block per 1024-segment window ----------
__global__ __launch_bounds__(256) void winsort_k(const int* __restrict__ rp,
                                                 int nseg,
                                                 int* __restrict__ perm) {
  __shared__ uint16_t kv[WIN];
  __shared__ uint32_t hist[64];
  const int base = blockIdx.x * WIN;
  const int cnt  = min(WIN, nseg - base);
  const int tid  = threadIdx.x;

  if (tid < 64) hist[tid] = 0;
  __syncthreads();

  for (int j = tid; j < cnt; j += 256) {
    const int deg = rp[base + j + 1] - rp[base + j];
    const int k = min((deg + 31) >> 5, 63);
    kv[j] = (uint16_t)k;
    atomicAdd(&hist[k], 1u);
  }
  __syncthreads();

  if (tid == 0) {                       // 64-entry serial prefix (trivial)
    uint32_t s = 0;
    for (int b = 0; b < 64; ++b) { const uint32_t c = hist[b]; hist[b] = s; s += c; }
  }
  __syncthreads();

  for (int j = tid; j < cnt; j += 256) {
    const uint32_t r = atomicAdd(&hist[kv[j]], 1u);   // hist doubles as cursor
    perm[base + r] = base + j;          // bijective within the window
  }
}

// ---- main kernel (v6 scan/merge, perm indirection) ----------------------
__global__ __launch_bounds__(256) void seg_top4_v8(
    const int* __restrict__ rp,
    const float* __restrict__ esc,
    float4* __restrict__ out_v,
    float4* __restrict__ out_i,
    const int* __restrict__ perm,    // may be nullptr (identity)
    int nseg, int E)
{
  const int lane = threadIdx.x & 63;
  const int g    = lane >> 3;          // group (segment slot) within wave: 0..7
  const int t    = lane & 7;           // lane within 8-lane group
  const int w    = (int)((blockIdx.x * (unsigned)blockDim.x + threadIdx.x) >> 6);
  const int pos  = (w << 3) + g;
  const int posc = min(pos, nseg - 1);
  const int seg  = perm ? perm[posc] : posc;

  const int lo  = rp[seg];
  const int hi  = rp[seg + 1];
  const int deg = hi - lo;             // group-uniform

  const float NEG = __int_as_float(0xFF800000u);   // -inf sentinel
  float av0 = NEG, av1 = NEG, av2 = NEG, av3 = NEG;
  int   ai0 = -1,  ai1 = -1,  ai2 = -1,  ai3 = -1;

  // med3 sorted-quad insert: values 4 inst, indices via masks on OLD vals.
#define INS4(V, EIDX) do {                                       \
    const float _v = (V); const int _e = (EIDX);                 \
    const bool c0 = _v > av0;                                    \
    const bool c1 = _v > av1;                                    \
    const bool c2 = _v > av2;                                    \
    const bool c3 = _v > av3;                                    \
    const int n0 = c0 ? _e  : ai0;                               \
    const int n1 = c0 ? ai0 : (c1 ? _e : ai1);                   \
    const int n2 = c1 ? ai1 : (c2 ? _e : ai2);                   \
    const int n3 = c2 ? ai2 : (c3 ? _e : ai3);                   \
    const float m1 = __builtin_amdgcn_fmed3f(_v, av0, av1);      \
    const float m2 = __builtin_amdgcn_fmed3f(_v, av1, av2);      \
    const float m3 = __builtin_amdgcn_fmed3f(_v, av2, av3);      \
    av0 = fmaxf(av0, _v);                                        \
    av1 = m1; av2 = m2; av3 = m3;                                \
    ai0 = n0; ai1 = n1; ai2 = n2; ai3 = n3;                      \
  } while (0)

#define PROC(F, QS, REL) do {                                            \
    const float v0 = ((unsigned)((REL) + 0) < (unsigned)deg) ? (F).x : NEG; \
    const float v1 = ((unsigned)((REL) + 1) < (unsigned)deg) ? (F).y : NEG; \
    const float v2 = ((unsigned)((REL) + 2) < (unsigned)deg) ? (F).z : NEG; \
    const float v3 = ((unsigned)((REL) + 3) < (unsigned)deg) ? (F).w : NEG; \
    INS4(v0, (QS) + 0);                                                  \
    INS4(v1, (QS) + 1);                                                  \
    INS4(v2, (QS) + 2);                                                  \
    INS4(v3, (QS) + 3);                                                  \
  } while (0)

  // ---- scan: depth-2 pipelined aligned float4, 32 elems/group-iter -------
  const int Ec = E - 4;                // 4-aligned (E % 4 == 0)
  int qs  = (lo & ~3) + (t << 2);      // 4-aligned quad start for this lane
  int rel = qs - lo;                   // offset within segment (may be <0)

  float4 f  = *reinterpret_cast<const float4*>(esc + min(qs, Ec));
  float4 fn = *reinterpret_cast<const float4*>(esc + min(qs + 32, Ec));

  while (__any(qs < hi)) {
    const float4 fnn =
        *reinterpret_cast<const float4*>(esc + min(qs + 64, Ec));
    PROC(f, qs, rel);
    f = fn; fn = fnn;
    qs  += 32;
    rel += 32;
  }
#undef PROC
#undef INS4

  // ---- merge: 4 rounds of 8-lane DPP extract-max, min-idx tie-break ------
  float rv0, rv1, rv2, rv3;
  int   ri0, ri1, ri2, ri3;
  #pragma unroll
  for (int r = 0; r < 4; ++r) {
    const float M = grpmax8(av0);
    const int   c = (av0 == M) ? ai0 : 0x7FFFFFFF;
    const int   W = grpmin8(c);              // stable: min original idx wins
    if (r == 0)      { rv0 = M; ri0 = W; }
    else if (r == 1) { rv1 = M; ri1 = W; }
    else if (r == 2) { rv2 = M; ri2 = W; }
    else             { rv3 = M; ri3 = W; }
    if (r < 3) {
      const bool p = (c == W);   // exactly the winning lane; idx unique
      av0 = p ? av1 : av0; ai0 = p ? ai1 : ai0;
      av1 = p ? av2 : av1; ai1 = p ? ai2 : ai1;
      av2 = p ? av3 : av2; ai2 = p ? ai3 : ai2;
    }
  }

  // ---- epilogue: lane 0 of each group writes two float4 ------------------
  if (t == 0 && pos < nseg) {
    float4 vv, ii;
    vv.x = (0 < deg) ? rv0 : -1.0e38f;  ii.x = (0 < deg) ? (float)ri0 : -1.0f;
    vv.y = (1 < deg) ? rv1 : -1.0e38f;  ii.y = (1 < deg) ? (float)ri1 : -1.0f;
    vv.z = (2 < deg) ? rv2 : -1.0e38f;  ii.z = (2 < deg) ? (float)ri2 : -1.0f;
    vv.w = (3 < deg) ? rv3 : -1.0e38f;  ii.w = (3 < deg) ? (float)ri3 : -1.0f;
    out_v[seg] = vv;     // pads stay bf16-finite: -1.0e38f -> bf16 0xFF16
    out_i[seg] = ii;
  }
}

extern "C" void kernel_launch(void* const* d_in, const int* in_sizes, int n_in,
                              void* d_out, int out_size, void* d_ws, size_t ws_size,
                              hipStream_t stream) {
  const int*   rp  = (const int*)d_in[0];    // row_ptr [N+1]
  const float* esc = (const float*)d_in[1];  // edge_scores [E]
  const int   nseg = in_sizes[0] - 1;
  const int   E    = in_sizes[1];

  float4* out_v = (float4*)d_out;                                  // vals [N]
  float4* out_i = (float4*)((float*)d_out + (size_t)nseg * 4);     // idx  [N]

  const int segs_per_block = 32;   // 256 threads = 4 waves = 32 segments
  const int grid = (nseg + segs_per_block - 1) / segs_per_block;

  if (ws_size >= (size_t)nseg * 4) {
    int* perm = (int*)d_ws;
    const int nwin = (nseg + WIN - 1) / WIN;
    winsort_k<<<nwin, 256, 0, stream>>>(rp, nseg, perm);
    seg_top4_v8<<<grid, 256, 0, stream>>>(rp, esc, out_v, out_i, perm, nseg, E);
  } else {
    seg_top4_v8<<<grid, 256, 0, stream>>>(rp, esc, out_v, out_i, nullptr, nseg, E);
  }
}

// Round 14
// 76.742 us; speedup vs baseline: 1.5824x; 1.5824x over previous
//
#include <hip/hip_runtime.h>
#include <stdint.h>

// Segmented top-4 over CSR (N=500K segments, E=32M edges).
// d_out = f32: [N*4 topk_vals][N*4 topk_idx-as-float], 16 MB.
// Pads MUST be bf16-finite (checker compares in bf16; -inf pad => nan).
//
// v9 = v6 (best: identity order, 8 segs x 8 lanes per wave) with a 2x
// unrolled, dual-prefetch scan loop (halved loop-control cost, no register
// rotation in the dependence chain). NO segment permutation: R12/R13 proved
// any reordering destroys stream/write locality and regresses 1.5x.
// Scan: aligned float4/lane, branch-free range mask, v_med3_f32 sorted-quad
// insert. Merge: 4 rounds of 8-lane DPP extract-max with min-idx tie-break
// (stable == jnp.lexsort((-scores, seg))). Lane 0 writes two float4s.

template <int CTRL>
__device__ __forceinline__ float dppf(float x) {
  int r = __builtin_amdgcn_update_dpp(__float_as_int(x), __float_as_int(x),
                                      CTRL, 0xF, 0xF, false);
  return __int_as_float(r);
}
template <int CTRL>
__device__ __forceinline__ int dppi(int x) {
  return __builtin_amdgcn_update_dpp(x, x, CTRL, 0xF, 0xF, false);
}

// 8-lane reductions: quad_perm xor1 (0xB1), xor2 (0x4E), row_half_mirror
// (0x141) — all stay inside the 8-lane group.
__device__ __forceinline__ float grpmax8(float x) {
  x = fmaxf(x, dppf<0xB1>(x));
  x = fmaxf(x, dppf<0x4E>(x));
  x = fmaxf(x, dppf<0x141>(x));
  return x;
}
__device__ __forceinline__ int grpmin8(int x) {
  x = min(x, dppi<0xB1>(x));
  x = min(x, dppi<0x4E>(x));
  x = min(x, dppi<0x141>(x));
  return x;
}

__global__ __launch_bounds__(256) void seg_top4_v9(
    const int* __restrict__ rp,
    const float* __restrict__ esc,
    float4* __restrict__ out_v,
    float4* __restrict__ out_i,
    int nseg, int E)
{
  const int lane = threadIdx.x & 63;
  const int g    = lane >> 3;          // group (segment slot) within wave: 0..7
  const int t    = lane & 7;           // lane within 8-lane group
  const int w    = (int)((blockIdx.x * (unsigned)blockDim.x + threadIdx.x) >> 6);
  const int seg  = (w << 3) + g;
  if (seg >= nseg) return;             // never fires (N % 8 == 0), safety only

  const int lo  = rp[seg];
  const int hi  = rp[seg + 1];
  const int deg = hi - lo;             // group-uniform

  const float NEG = __int_as_float(0xFF800000u);   // -inf sentinel
  float av0 = NEG, av1 = NEG, av2 = NEG, av3 = NEG;
  int   ai0 = -1,  ai1 = -1,  ai2 = -1,  ai3 = -1;

  // med3 sorted-quad insert: values 4 inst, indices via masks on OLD vals.
#define INS4(V, EIDX) do {                                       \
    const float _v = (V); const int _e = (EIDX);                 \
    const bool c0 = _v > av0;                                    \
    const bool c1 = _v > av1;                                    \
    const bool c2 = _v > av2;                                    \
    const bool c3 = _v > av3;                                    \
    const int n0 = c0 ? _e  : ai0;                               \
    const int n1 = c0 ? ai0 : (c1 ? _e : ai1);                   \
    const int n2 = c1 ? ai1 : (c2 ? _e : ai2);                   \
    const int n3 = c2 ? ai2 : (c3 ? _e : ai3);                   \
    const float m1 = __builtin_amdgcn_fmed3f(_v, av0, av1);      \
    const float m2 = __builtin_amdgcn_fmed3f(_v, av1, av2);      \
    const float m3 = __builtin_amdgcn_fmed3f(_v, av2, av3);      \
    av0 = fmaxf(av0, _v);                                        \
    av1 = m1; av2 = m2; av3 = m3;                                \
    ai0 = n0; ai1 = n1; ai2 = n2; ai3 = n3;                      \
  } while (0)

#define PROC(F, QS, REL) do {                                            \
    const float v0 = ((unsigned)((REL) + 0) < (unsigned)deg) ? (F).x : NEG; \
    const float v1 = ((unsigned)((REL) + 1) < (unsigned)deg) ? (F).y : NEG; \
    const float v2 = ((unsigned)((REL) + 2) < (unsigned)deg) ? (F).z : NEG; \
    const float v3 = ((unsigned)((REL) + 3) < (unsigned)deg) ? (F).w : NEG; \
    INS4(v0, (QS) + 0);                                                  \
    INS4(v1, (QS) + 1);                                                  \
    INS4(v2, (QS) + 2);                                                  \
    INS4(v3, (QS) + 3);                                                  \
  } while (0)

  // ---- scan: 2x-unrolled dual-prefetch aligned float4, 64 elems/iter -----
  const int Ec = E - 4;                // 4-aligned (E % 4 == 0)
  int qs  = (lo & ~3) + (t << 2);      // 4-aligned quad start for this lane
  int rel = qs - lo;                   // offset within segment (may be <0)

  float4 f  = *reinterpret_cast<const float4*>(esc + min(qs, Ec));
  float4 fn = *reinterpret_cast<const float4*>(esc + min(qs + 32, Ec));

  while (__any(qs < hi)) {
    // issue both next-window loads before consuming the current ones
    const float4 p1 = *reinterpret_cast<const float4*>(esc + min(qs + 64, Ec));
    const float4 p2 = *reinterpret_cast<const float4*>(esc + min(qs + 96, Ec));
    PROC(f, qs, rel);
    PROC(fn, qs + 32, rel + 32);       // possibly past hi: range-mask -> NEG
    f = p1; fn = p2;
    qs  += 64;
    rel += 64;
  }
#undef PROC
#undef INS4

  // ---- merge: 4 rounds of 8-lane DPP extract-max, min-idx tie-break ------
  float rv0, rv1, rv2, rv3;
  int   ri0, ri1, ri2, ri3;
  #pragma unroll
  for (int r = 0; r < 4; ++r) {
    const float M = grpmax8(av0);
    const int   c = (av0 == M) ? ai0 : 0x7FFFFFFF;
    const int   W = grpmin8(c);              // stable: min original idx wins
    if (r == 0)      { rv0 = M; ri0 = W; }
    else if (r == 1) { rv1 = M; ri1 = W; }
    else if (r == 2) { rv2 = M; ri2 = W; }
    else             { rv3 = M; ri3 = W; }
    if (r < 3) {
      const bool p = (c == W);   // exactly the winning lane; idx unique
      av0 = p ? av1 : av0; ai0 = p ? ai1 : ai0;
      av1 = p ? av2 : av1; ai1 = p ? ai2 : ai1;
      av2 = p ? av3 : av2; ai2 = p ? ai3 : ai2;
      // av3 left stale: a lane pops at most 3 times before round 3 reads av0
    }
  }

  // ---- epilogue: lane 0 of each group writes two float4 ------------------
  if (t == 0) {
    float4 vv, ii;
    vv.x = (0 < deg) ? rv0 : -1.0e38f;  ii.x = (0 < deg) ? (float)ri0 : -1.0f;
    vv.y = (1 < deg) ? rv1 : -1.0e38f;  ii.y = (1 < deg) ? (float)ri1 : -1.0f;
    vv.z = (2 < deg) ? rv2 : -1.0e38f;  ii.z = (2 < deg) ? (float)ri2 : -1.0f;
    vv.w = (3 < deg) ? rv3 : -1.0e38f;  ii.w = (3 < deg) ? (float)ri3 : -1.0f;
    out_v[seg] = vv;     // pads stay bf16-finite: -1.0e38f -> bf16 0xFF16
    out_i[seg] = ii;
  }
}

extern "C" void kernel_launch(void* const* d_in, const int* in_sizes, int n_in,
                              void* d_out, int out_size, void* d_ws, size_t ws_size,
                              hipStream_t stream) {
  const int*   rp  = (const int*)d_in[0];    // row_ptr [N+1]
  const float* esc = (const float*)d_in[1];  // edge_scores [E]
  const int   nseg = in_sizes[0] - 1;
  const int   E    = in_sizes[1];

  float4* out_v = (float4*)d_out;                                  // vals [N]
  float4* out_i = (float4*)((float*)d_out + (size_t)nseg * 4);     // idx  [N]

  const int segs_per_block = 32;   // 256 threads = 4 waves = 32 segments
  const int grid = (nseg + segs_per_block - 1) / segs_per_block;
  seg_top4_v9<<<grid, 256, 0, stream>>>(rp, esc, out_v, out_i, nseg, E);
}

// Round 15
// 74.943 us; speedup vs baseline: 1.6204x; 1.0240x over previous
//
#include <hip/hip_runtime.h>
#include <stdint.h>

// Segmented top-4 over CSR (N=500K segments, E=32M edges).
// d_out = f32: [N*4 topk_vals][N*4 topk_idx-as-float], 16 MB.
// Pads MUST be bf16-finite (checker compares in bf16; -inf pad => nan).
//
// v10 = v9 + depth-2 prefetch (4 windows in flight; load->use distance ~2
// full iterations) + clamp-free fast path for waves that provably never
// reach the array end (all but the last wave: immediate-offset addressing,
// no min-clamps). Per-element range mask retained everywhere (correctness).
// Scan: aligned float4/lane, v_med3_f32 sorted-quad insert. Merge: 4 rounds
// of 8-lane DPP extract-max with min-idx tie-break (== lexsort((-s, seg))).

template <int CTRL>
__device__ __forceinline__ float dppf(float x) {
  int r = __builtin_amdgcn_update_dpp(__float_as_int(x), __float_as_int(x),
                                      CTRL, 0xF, 0xF, false);
  return __int_as_float(r);
}
template <int CTRL>
__device__ __forceinline__ int dppi(int x) {
  return __builtin_amdgcn_update_dpp(x, x, CTRL, 0xF, 0xF, false);
}

// 8-lane reductions: quad_perm xor1 (0xB1), xor2 (0x4E), row_half_mirror
// (0x141) — all stay inside the 8-lane group.
__device__ __forceinline__ float grpmax8(float x) {
  x = fmaxf(x, dppf<0xB1>(x));
  x = fmaxf(x, dppf<0x4E>(x));
  x = fmaxf(x, dppf<0x141>(x));
  return x;
}
__device__ __forceinline__ int grpmin8(int x) {
  x = min(x, dppi<0xB1>(x));
  x = min(x, dppi<0x4E>(x));
  x = min(x, dppi<0x141>(x));
  return x;
}

__global__ __launch_bounds__(256) void seg_top4_v10(
    const int* __restrict__ rp,
    const float* __restrict__ esc,
    float4* __restrict__ out_v,
    float4* __restrict__ out_i,
    int nseg, int E)
{
  const int lane = threadIdx.x & 63;
  const int g    = lane >> 3;          // group (segment slot) within wave: 0..7
  const int t    = lane & 7;           // lane within 8-lane group
  const int w    = (int)((blockIdx.x * (unsigned)blockDim.x + threadIdx.x) >> 6);
  const int seg  = (w << 3) + g;
  if (seg >= nseg) return;             // never fires (N % 8 == 0), safety only

  const int lo  = rp[seg];
  const int hi  = rp[seg + 1];
  const int deg = hi - lo;             // group-uniform

  const float NEG = __int_as_float(0xFF800000u);   // -inf sentinel
  float av0 = NEG, av1 = NEG, av2 = NEG, av3 = NEG;
  int   ai0 = -1,  ai1 = -1,  ai2 = -1,  ai3 = -1;

  // med3 sorted-quad insert: values 4 inst, indices via masks on OLD vals.
#define INS4(V, EIDX) do {                                       \
    const float _v = (V); const int _e = (EIDX);                 \
    const bool c0 = _v > av0;                                    \
    const bool c1 = _v > av1;                                    \
    const bool c2 = _v > av2;                                    \
    const bool c3 = _v > av3;                                    \
    const int n0 = c0 ? _e  : ai0;                               \
    const int n1 = c0 ? ai0 : (c1 ? _e : ai1);                   \
    const int n2 = c1 ? ai1 : (c2 ? _e : ai2);                   \
    const int n3 = c2 ? ai2 : (c3 ? _e : ai3);                   \
    const float m1 = __builtin_amdgcn_fmed3f(_v, av0, av1);      \
    const float m2 = __builtin_amdgcn_fmed3f(_v, av1, av2);      \
    const float m3 = __builtin_amdgcn_fmed3f(_v, av2, av3);      \
    av0 = fmaxf(av0, _v);                                        \
    av1 = m1; av2 = m2; av3 = m3;                                \
    ai0 = n0; ai1 = n1; ai2 = n2; ai3 = n3;                      \
  } while (0)

#define PROC(F, QS, REL) do {                                            \
    const float v0 = ((unsigned)((REL) + 0) < (unsigned)deg) ? (F).x : NEG; \
    const float v1 = ((unsigned)((REL) + 1) < (unsigned)deg) ? (F).y : NEG; \
    const float v2 = ((unsigned)((REL) + 2) < (unsigned)deg) ? (F).z : NEG; \
    const float v3 = ((unsigned)((REL) + 3) < (unsigned)deg) ? (F).w : NEG; \
    INS4(v0, (QS) + 0);                                                  \
    INS4(v1, (QS) + 1);                                                  \
    INS4(v2, (QS) + 2);                                                  \
    INS4(v3, (QS) + 3);                                                  \
  } while (0)

  int qs  = (lo & ~3) + (t << 2);      // 4-aligned quad start for this lane
  int rel = qs - lo;                   // offset within segment (may be <0)

  // Fast path iff NO load this wave can ever pass the array end:
  // final qs < max_hi + 64; deepest prefetch reads qs+160..qs+163.
  if (__all(hi + 228 <= E)) {
    const float4* bp = reinterpret_cast<const float4*>(esc + qs);
    float4 f0 = bp[0];                 // qs +  0
    float4 f1 = bp[8];                 // qs + 32
    float4 f2 = bp[16];                // qs + 64
    float4 f3 = bp[24];                // qs + 96
    while (__any(qs < hi)) {
      const float4 p0 = bp[32];        // qs + 128 (2 iterations ahead)
      const float4 p1 = bp[40];        // qs + 160
      PROC(f0, qs, rel);
      PROC(f1, qs + 32, rel + 32);     // possibly past hi: range-mask -> NEG
      f0 = f2; f1 = f3; f2 = p0; f3 = p1;
      bp  += 16;                       // +64 floats
      qs  += 64;
      rel += 64;
    }
  } else {
    // v9 body: clamped loads, depth-1 prefetch (only the last wave or two)
    const int Ec = E - 4;              // 4-aligned (E % 4 == 0)
    float4 f  = *reinterpret_cast<const float4*>(esc + min(qs, Ec));
    float4 fn = *reinterpret_cast<const float4*>(esc + min(qs + 32, Ec));
    while (__any(qs < hi)) {
      const float4 p1 = *reinterpret_cast<const float4*>(esc + min(qs + 64, Ec));
      const float4 p2 = *reinterpret_cast<const float4*>(esc + min(qs + 96, Ec));
      PROC(f, qs, rel);
      PROC(fn, qs + 32, rel + 32);
      f = p1; fn = p2;
      qs  += 64;
      rel += 64;
    }
  }
#undef PROC
#undef INS4

  // ---- merge: 4 rounds of 8-lane DPP extract-max, min-idx tie-break ------
  float rv0, rv1, rv2, rv3;
  int   ri0, ri1, ri2, ri3;
  #pragma unroll
  for (int r = 0; r < 4; ++r) {
    const float M = grpmax8(av0);
    const int   c = (av0 == M) ? ai0 : 0x7FFFFFFF;
    const int   W = grpmin8(c);              // stable: min original idx wins
    if (r == 0)      { rv0 = M; ri0 = W; }
    else if (r == 1) { rv1 = M; ri1 = W; }
    else if (r == 2) { rv2 = M; ri2 = W; }
    else             { rv3 = M; ri3 = W; }
    if (r < 3) {
      const bool p = (c == W);   // exactly the winning lane; idx unique
      av0 = p ? av1 : av0; ai0 = p ? ai1 : ai0;
      av1 = p ? av2 : av1; ai1 = p ? ai2 : ai1;
      av2 = p ? av3 : av2; ai2 = p ? ai3 : ai2;
      // av3 left stale: a lane pops at most 3 times before round 3 reads av0
    }
  }

  // ---- epilogue: lane 0 of each group writes two float4 ------------------
  if (t == 0) {
    float4 vv, ii;
    vv.x = (0 < deg) ? rv0 : -1.0e38f;  ii.x = (0 < deg) ? (float)ri0 : -1.0f;
    vv.y = (1 < deg) ? rv1 : -1.0e38f;  ii.y = (1 < deg) ? (float)ri1 : -1.0f;
    vv.z = (2 < deg) ? rv2 : -1.0e38f;  ii.z = (2 < deg) ? (float)ri2 : -1.0f;
    vv.w = (3 < deg) ? rv3 : -1.0e38f;  ii.w = (3 < deg) ? (float)ri3 : -1.0f;
    out_v[seg] = vv;     // pads stay bf16-finite: -1.0e38f -> bf16 0xFF16
    out_i[seg] = ii;
  }
}

extern "C" void kernel_launch(void* const* d_in, const int* in_sizes, int n_in,
                              void* d_out, int out_size, void* d_ws, size_t ws_size,
                              hipStream_t stream) {
  const int*   rp  = (const int*)d_in[0];    // row_ptr [N+1]
  const float* esc = (const float*)d_in[1];  // edge_scores [E]
  const int   nseg = in_sizes[0] - 1;
  const int   E    = in_sizes[1];

  float4* out_v = (float4*)d_out;                                  // vals [N]
  float4* out_i = (float4*)((float*)d_out + (size_t)nseg * 4);     // idx  [N]

  const int segs_per_block = 32;   // 256 threads = 4 waves = 32 segments
  const int grid = (nseg + segs_per_block - 1) / segs_per_block;
  seg_top4_v10<<<grid, 256, 0, stream>>>(rp, esc, out_v, out_i, nseg, E);
}